// Round 11
// baseline (273.628 us; speedup 1.0000x reference)
//
#include <hip/hip_runtime.h>

typedef short bf16x8 __attribute__((ext_vector_type(8)));
typedef float f32x16 __attribute__((ext_vector_type(16)));
typedef unsigned short u16;
typedef u16 ushort8v __attribute__((ext_vector_type(8)));

// ---- constants ----
#define VOCAB 100000
#define EMB 300
#define SEQ 40
#define BATCH 8192
#define COUT 210
#define NBLK 5
#define KPOOL 38
#define DH 35
#define NCLS 35
#define PCOL 320            // padded w2v row: 300 real + 20 zero (16B-aligned rows)
#define NUSE 192            // only channels 0..189 feed the pool
#define BM 128              // always spans exactly 4 batches
#define ER 168              // 4 x 42 padded embedding rows resident in LDS
#define NGR 120             // total K granules (3 kh x 40)

__device__ __forceinline__ u16 f2bf(float f) {
  unsigned u = __float_as_uint(f);
  unsigned r = 0x7FFFu + ((u >> 16) & 1u);
  return (u16)((u + r) >> 16);
}

__device__ __forceinline__ void gload_lds16(void* lds, const void* g) {
  __builtin_amdgcn_global_load_lds(
      (const __attribute__((address_space(1))) void*)g,
      (__attribute__((address_space(3))) void*)lds, 16, 0, 0);
}

// ---- kernel 1: w2v f32 [VOCAB][300] -> W bf16 [VOCAB+1][320]; row VOCAB = zeros ----
__global__ __launch_bounds__(256) void k_prepW(const float* __restrict__ w2v,
                                               u16* __restrict__ W) {
  int id = blockIdx.x * 256 + threadIdx.x;          // (VOCAB+1)*40 chunks of 8
  if (id >= (VOCAB + 1) * 40) return;
  int v = id / 40, e8 = id - v * 40;
  int e = e8 * 8;
  float vals[8] = {0.f, 0.f, 0.f, 0.f, 0.f, 0.f, 0.f, 0.f};
  if (v < VOCAB) {
    const float* src = w2v + (size_t)v * EMB + e;
    if (e <= 292) {
      float4 f0 = *(const float4*)src;
      float4 f1 = *(const float4*)(src + 4);
      vals[0] = f0.x; vals[1] = f0.y; vals[2] = f0.z; vals[3] = f0.w;
      vals[4] = f1.x; vals[5] = f1.y; vals[6] = f1.z; vals[7] = f1.w;
    } else if (e == 296) {
      float4 f0 = *(const float4*)src;               // 296..299
      vals[0] = f0.x; vals[1] = f0.y; vals[2] = f0.z; vals[3] = f0.w;
    }
  }
  ushort8v o;
#pragma unroll
  for (int j = 0; j < 8; ++j) o[j] = f2bf(vals[j]);
  *(ushort8v*)(W + (size_t)v * PCOL + e) = o;
}

// ---- kernel 2: conv_w [3][300][210] -> Btn bf16 [120 gran][192 col][8] (zero padded) ----
__global__ __launch_bounds__(256) void k_prepB(const float* __restrict__ convw,
                                               u16* __restrict__ Btn) {
  int id = blockIdx.x * 256 + threadIdx.x;          // 120*192 = 23040
  if (id >= NGR * NUSE) return;
  int gg = id / NUSE, col = id - gg * NUSE;
  ushort8v o;
#pragma unroll
  for (int j = 0; j < 8; ++j) {
    int k = gg * 8 + j;
    int kh = (k >= 640) ? 2 : (k >= 320 ? 1 : 0);
    int e = k - kh * PCOL;
    float v = (e < EMB) ? convw[(kh * EMB + e) * COUT + col] : 0.f;
    o[j] = f2bf(v);
  }
  *(ushort8v*)(Btn + (size_t)id * 8) = o;
}

// ---- kernel 3: fused gather + conv (3 shifted sub-GEMMs) + bias/relu/pool ----
// 32x32x16 MFMA, BM=128 (4 batches), 512 threads = 8 waves as 4M x 2N, wave tile
// 32x96 (acc[3] f32x16). K-sweep split into 2 GRANULE PHASES (gran 0..19 / 20..39;
// K-order commutative): each phase stages 20 gran x 168 rows = 53,760 B into ONE
// reused LDS buffer (stage -> barrier -> 30 pure ds_read+MFMA steps -> barrier).
// Halved LDS -> 2 blocks/CU, so staging stalls overlap the sibling block's compute
// (r8 lesson: 1 block/CU exposes the gather prologue; occupancy 23% -> ~50%).
__global__ __launch_bounds__(512) void k_conv_gemm(const u16* __restrict__ Wb,
                                                   const u16* __restrict__ Btn,
                                                   const int* __restrict__ x,
                                                   const float* __restrict__ convb,
                                                   float* __restrict__ maxc) {
  __shared__ __align__(16) char smem[20 * ER * 16];   // 53,760 B; epilogue aliases act
  float* act = (float*)smem;                           // [32][194] = 24,832 B

  const int tid = threadIdx.x;
  const int lane = tid & 63;
  const int w = tid >> 6;
  const int wm = w >> 1, wn = w & 1;                  // 4M x 2N wave grid
  const int l31 = lane & 31, h = lane >> 5;
  const int m0 = blockIdx.x * BM;
  const int blo = m0 / SEQ;                           // block spans batches blo..blo+3

  // ---- per-lane A base: row m = m0 + wm*32 + l31; prow = (b-blo)*42 + s (+kh later) ----
  int aBase;
  {
    const int m = m0 + wm * 32 + l31;
    const int bA = m / SEQ, sA = m - bA * SEQ;
    aBase = ((h * ER) + (bA - blo) * 42 + sA) * 16;   // bytes
  }
  // ---- per-lane B offset (elements): granule h, col = wn*96 + fn*32 + l31 ----
  const int bElem = (h * NUSE + wn * 96 + l31) * 8;

  f32x16 acc[3];
  const f32x16 zero16 = {0.f,0.f,0.f,0.f,0.f,0.f,0.f,0.f,0.f,0.f,0.f,0.f,0.f,0.f,0.f,0.f};
#pragma unroll
  for (int j = 0; j < 3; ++j) acc[j] = zero16;

  bf16x8 aR[2];
  bf16x8 bS[3][3];                                    // 3 rotating B sets

#define LOADA(SLOT, J)                                                         \
  aR[SLOT] = *(const bf16x8*)(smem + aBase + ((2 * ((J) % 10)) * ER + (J) / 10) * 16);

#define LOADB(SI, T)                                                           \
  {                                                                            \
    const u16* p_ = Btn + (size_t)(T) * 3072 + bElem;                          \
    bS[SI][0] = *(const bf16x8*)(p_);                                          \
    bS[SI][1] = *(const bf16x8*)(p_ + 256);                                    \
    bS[SI][2] = *(const bf16x8*)(p_ + 512);                                    \
  }

#pragma unroll
  for (int p = 0; p < 2; ++p) {
    // ---- stage this phase's E-tile half: chunk c=(g_local*ER+prow), 3360 chunks ----
#pragma unroll
    for (int ri = 0; ri < 6; ++ri) {
      const int c = ri * 512 + tid;                   // 0..3071
      const int g = c / ER, prow = c - g * ER;
      const int bb = prow / 42, sp = prow - bb * 42;
      const int tok = (sp == 0 || sp == 41) ? VOCAB : x[(blo + bb) * SEQ + sp - 1];
      gload_lds16(smem + c * 16, Wb + (size_t)tok * PCOL + (20 * p + g) * 8);
    }
    if (tid < 288) {                                  // 3072..3359
      const int c = 3072 + tid;
      const int g = c / ER, prow = c - g * ER;
      const int bb = prow / 42, sp = prow - bb * 42;
      const int tok = (sp == 0 || sp == 41) ? VOCAB : x[(blo + bb) * SEQ + sp - 1];
      gload_lds16(smem + c * 16, Wb + (size_t)tok * PCOL + (20 * p + g) * 8);
    }
    LOADB(0, p * 10)                                  // B tiles for steps j=0,1
    LOADB(1, p * 10 + 1)
    __syncthreads();                                  // drains vmcnt -> half-tile resident
    LOADA(0, 0)

    // ---- 30 steps: kh = j/10, tq = j%10; B tile T = kh*20 + p*10 + tq ----
#pragma unroll
    for (int j = 0; j < 30; ++j) {
      if (j + 1 < 30) { LOADA((j + 1) & 1, j + 1) }
      if (j + 2 < 30) {
        const int jj = j + 2;
        LOADB(jj % 3, (jj / 10) * 20 + p * 10 + (jj % 10))
      }
      __builtin_amdgcn_s_setprio(1);
#pragma unroll
      for (int fn = 0; fn < 3; ++fn)
        acc[fn] = __builtin_amdgcn_mfma_f32_32x32x16_bf16(aR[j & 1], bS[j % 3][fn], acc[fn], 0, 0, 0);
      __builtin_amdgcn_s_setprio(0);
    }
    __syncthreads();                                  // phase reads done (restage / act alias)
  }
#undef LOADA
#undef LOADB

  // ---- epilogue: 4 chunks of 32 rows (chunk ch = waves wm==ch); bias+relu -> LDS
  //      -> per-(row,group) max over 38 channels. All acc indices compile-time.
#pragma unroll
  for (int ch = 0; ch < 4; ++ch) {
    if (wm == ch) {
#pragma unroll
      for (int fn = 0; fn < 3; ++fn) {
        const int col = wn * 96 + fn * 32 + l31;      // < 192 < 210
        const float bias = convb[col];
#pragma unroll
        for (int r = 0; r < 16; ++r) {
          const int row = (r & 3) + 8 * (r >> 2) + 4 * h;   // verified C/D layout (m74/m101)
          act[row * 194 + col] = fmaxf(acc[fn][r] + bias, 0.f);
        }
      }
    }
    __syncthreads();
    if (tid < 160) {                                  // 32 rows x 5 groups
      const int rl = tid / 5, gq = tid - rl * 5;
      const float* ap = act + rl * 194 + gq * KPOOL;
      float mx = 0.f;                                 // relu => values >= 0
#pragma unroll
      for (int i = 0; i < KPOOL; ++i) mx = fmaxf(mx, ap[i]);
      const int m = m0 + ch * 32 + rl;
      const int bb = m / SEQ, ss = m - bb * SEQ;
      maxc[(bb * NBLK + gq) * SEQ + ss] = mx;         // unmasked max; mask applied in k_dense
    }
    __syncthreads();
  }
}

// ---- kernel 4: region-masked dense (120->35) + out (35->35) ----
__global__ __launch_bounds__(256) void k_dense(const float* __restrict__ maxc,
                                               const int* __restrict__ pos,
                                               const float* __restrict__ dw,
                                               const float* __restrict__ db,
                                               const float* __restrict__ ow,
                                               const float* __restrict__ ob,
                                               float* __restrict__ out) {
  __shared__ float dwL[120 * 36];
  __shared__ float owL[35 * 36];
  __shared__ float hL[64 * 36];
  __shared__ float mxL[64 * 40];
  const int tid = threadIdx.x;
  const int r0 = blockIdx.x * 64;                    // 640 blocks x 64 rows
  for (int i = tid; i < 120 * 35; i += 256) { int j = i / 35, d = i - j * 35; dwL[j * 36 + d] = dw[i]; }
  for (int i = tid; i < 35 * 35; i += 256)  { int j = i / 35, d = i - j * 35; owL[j * 36 + d] = ow[i]; }
  for (int i = tid; i < 64 * 40; i += 256)  mxL[i] = maxc[(size_t)r0 * 40 + i];
  __syncthreads();
  for (int t = tid; t < 64 * 35; t += 256) {
    const int row = t / 35, d = t - row * 35;
    const int rg = r0 + row;
    const int b = rg / NBLK;
    const int p0 = pos[b * 2], p1 = pos[b * 2 + 1];
    int e1 = min(p0, p1), e2 = max(p0, p1);
    if (e1 == 0) { e1 = 1; e2 += 1; }
    float a = db[d];
#pragma unroll
    for (int s = 0; s < SEQ; ++s) {
      const int k = (s >= e1) + (s >= e2);           // region of position s
      a += mxL[row * 40 + s] * dwL[(k * SEQ + s) * 36 + d];
    }
    hL[row * 36 + d] = a;
  }
  __syncthreads();
  for (int t = tid; t < 64 * 35; t += 256) {
    const int row = t / 35, c = t - row * 35;
    float a = ob[c];
#pragma unroll
    for (int d = 0; d < DH; ++d) a += hL[row * 36 + d] * owL[d * 36 + c];
    out[(size_t)(r0 + row) * NCLS + c] = a;
  }
}

extern "C" void kernel_launch(void* const* d_in, const int* in_sizes, int n_in,
                              void* d_out, int out_size, void* d_ws, size_t ws_size,
                              hipStream_t stream) {
  const int*   x     = (const int*)d_in[0];
  const int*   pos   = (const int*)d_in[1];
  const float* w2v   = (const float*)d_in[2];
  const float* convw = (const float*)d_in[3];
  const float* convb = (const float*)d_in[4];
  const float* dw    = (const float*)d_in[5];
  const float* db    = (const float*)d_in[6];
  const float* ow    = (const float*)d_in[7];
  const float* ob    = (const float*)d_in[8];
  float* out = (float*)d_out;

  char* ws = (char*)d_ws;
  u16* W    = (u16*)ws;                               // (100001)*320*2 = 64,000,640 B
  u16* Btn  = (u16*)(ws + 64000640);                  // 120*192*8*2   =    368,640 B
  float* maxc = (float*)(ws + 64000640 + 368640);     // 40960*40*4    =  6,553,600 B

  k_prepW<<<15626, 256, 0, stream>>>(w2v, W);         // (100001*40+255)/256
  k_prepB<<<90, 256, 0, stream>>>(convw, Btn);        // 23040/256
  k_conv_gemm<<<2560, 512, 0, stream>>>(W, Btn, x, convb, maxc);  // 327680/128
  k_dense<<<640, 256, 0, stream>>>(maxc, pos, dw, db, ow, ob, out);
}

// Round 12
// 231.102 us; speedup vs baseline: 1.1840x; 1.1840x over previous
//
#include <hip/hip_runtime.h>

typedef short bf16x8 __attribute__((ext_vector_type(8)));
typedef float f32x16 __attribute__((ext_vector_type(16)));
typedef unsigned short u16;
typedef u16 ushort8v __attribute__((ext_vector_type(8)));

// ---- constants ----
#define VOCAB 100000
#define EMB 300
#define SEQ 40
#define BATCH 8192
#define COUT 210
#define NBLK 5
#define KPOOL 38
#define DH 35
#define NCLS 35
#define PCOL 320            // padded w2v row: 300 real + 20 zero (16B-aligned rows)
#define NUSE 192            // only channels 0..189 feed the pool
#define BM 128              // always spans exactly 4 batches
#define PR 180              // padded rows per granule in LDS (168 real + 12 pad: bank split)
#define NGR 120             // total K granules (3 kh x 40)

__device__ __forceinline__ u16 f2bf(float f) {
  unsigned u = __float_as_uint(f);
  unsigned r = 0x7FFFu + ((u >> 16) & 1u);
  return (u16)((u + r) >> 16);
}

__device__ __forceinline__ void gload_lds16(void* lds, const void* g) {
  __builtin_amdgcn_global_load_lds(
      (const __attribute__((address_space(1))) void*)g,
      (__attribute__((address_space(3))) void*)lds, 16, 0, 0);
}

// ---- kernel 1: w2v f32 [VOCAB][300] -> W bf16 [VOCAB+1][320]; row VOCAB = zeros ----
__global__ __launch_bounds__(256) void k_prepW(const float* __restrict__ w2v,
                                               u16* __restrict__ W) {
  int id = blockIdx.x * 256 + threadIdx.x;          // (VOCAB+1)*40 chunks of 8
  if (id >= (VOCAB + 1) * 40) return;
  int v = id / 40, e8 = id - v * 40;
  int e = e8 * 8;
  float vals[8] = {0.f, 0.f, 0.f, 0.f, 0.f, 0.f, 0.f, 0.f};
  if (v < VOCAB) {
    const float* src = w2v + (size_t)v * EMB + e;
    if (e <= 292) {
      float4 f0 = *(const float4*)src;
      float4 f1 = *(const float4*)(src + 4);
      vals[0] = f0.x; vals[1] = f0.y; vals[2] = f0.z; vals[3] = f0.w;
      vals[4] = f1.x; vals[5] = f1.y; vals[6] = f1.z; vals[7] = f1.w;
    } else if (e == 296) {
      float4 f0 = *(const float4*)src;               // 296..299
      vals[0] = f0.x; vals[1] = f0.y; vals[2] = f0.z; vals[3] = f0.w;
    }
  }
  ushort8v o;
#pragma unroll
  for (int j = 0; j < 8; ++j) o[j] = f2bf(vals[j]);
  *(ushort8v*)(W + (size_t)v * PCOL + e) = o;
}

// ---- kernel 2: conv_w [3][300][210] -> Btn bf16 [120 gran][192 col][8] (zero padded) ----
__global__ __launch_bounds__(256) void k_prepB(const float* __restrict__ convw,
                                               u16* __restrict__ Btn) {
  int id = blockIdx.x * 256 + threadIdx.x;          // 120*192 = 23040
  if (id >= NGR * NUSE) return;
  int gg = id / NUSE, col = id - gg * NUSE;
  ushort8v o;
#pragma unroll
  for (int j = 0; j < 8; ++j) {
    int k = gg * 8 + j;
    int kh = (k >= 640) ? 2 : (k >= 320 ? 1 : 0);
    int e = k - kh * PCOL;
    float v = (e < EMB) ? convw[(kh * EMB + e) * COUT + col] : 0.f;
    o[j] = f2bf(v);
  }
  *(ushort8v*)(Btn + (size_t)id * 8) = o;
}

// ---- kernel 3: fused gather + conv (3 shifted sub-GEMMs) + bias/relu/pool ----
// 32x32x16 MFMA. 256 threads = 4 waves as 4M x 1N (r7 lesson: 256-thread blocks
// co-reside; 512-thread ones pinned to 1 block/CU). Wave tile 32x192: per step
// 1 ds_read_b128 (A) + 6 B-frag global loads + 6 MFMA (48 cyc - self-covers B
// latency with prefetch-2; all 4 waves read identical B -> L1 broadcast).
// K-sweep: 4 phases x 10 granules; E staged per phase into one reused LDS buffer
// ([10 gran][180 rows]x16B; 180 splits h0/h1 bank sets -> <=4-way conflicts).
__global__ __launch_bounds__(256) void k_conv_gemm(const u16* __restrict__ Wb,
                                                   const u16* __restrict__ Btn,
                                                   const int* __restrict__ x,
                                                   const float* __restrict__ convb,
                                                   float* __restrict__ maxc) {
  __shared__ __align__(16) char smem[10 * PR * 16];   // 28,800 B; epilogue aliases act
  float* act = (float*)smem;                           // [32][194] = 24,832 B

  const int tid = threadIdx.x;
  const int lane = tid & 63;
  const int wm = tid >> 6;                            // wave = M-slot 0..3
  const int l31 = lane & 31, h = lane >> 5;
  const int m0 = blockIdx.x * BM;
  const int blo = m0 / SEQ;                           // block spans batches blo..blo+3

  // ---- per-lane A row: m = m0 + wm*32 + l31; prowA = (b-blo)*42 + s (+kh later) ----
  const int mrow = m0 + wm * 32 + l31;
  const int bA = mrow / SEQ, sA = mrow - bA * SEQ;
  const int prowA = (bA - blo) * 42 + sA;

  // ---- per-lane B base (elements): k-half h, col = fn*32 + l31 (fn adds 256) ----
  const int bElem0 = (h * NUSE + l31) * 8;

  // ---- staging slot offsets: chunk c = ri*256+tid -> (g=c/PR, prow=c%PR) ----
  // prow>=168 or seq-pad rows -> VOCAB (zero row). 7 rounds cover all real rows.
  unsigned s0, s1, s2, s3, s4, s5, s6;
  {
#define SLOT(SV, RI)                                                           \
    {                                                                          \
      const int c = (RI) * 256 + tid;                                          \
      const int g = c / PR, prow = c - g * PR;                                 \
      int tok = VOCAB;                                                         \
      if (prow < 168) {                                                        \
        const int bb = prow / 42, sp = prow - bb * 42;                         \
        tok = (sp == 0 || sp == 41) ? VOCAB : x[(blo + bb) * SEQ + sp - 1];    \
      }                                                                        \
      SV = (unsigned)tok * PCOL + g * 8;                                       \
    }
    SLOT(s0, 0) SLOT(s1, 1) SLOT(s2, 2) SLOT(s3, 3) SLOT(s4, 4) SLOT(s5, 5) SLOT(s6, 6)
#undef SLOT
  }

  f32x16 acc[6];
  const f32x16 zero16 = {0.f,0.f,0.f,0.f,0.f,0.f,0.f,0.f,0.f,0.f,0.f,0.f,0.f,0.f,0.f,0.f};
#pragma unroll
  for (int j = 0; j < 6; ++j) acc[j] = zero16;

  bf16x8 aR[2];
  bf16x8 bS[3][6];                                    // 3 rotating B sets (24 VGPR each)

#define LOADB(SI, TG)                                                          \
  {                                                                            \
    const u16* p_ = Btn + (size_t)(TG) * 3072 + bElem0;                        \
    bS[SI][0] = *(const bf16x8*)(p_);                                          \
    bS[SI][1] = *(const bf16x8*)(p_ + 256);                                    \
    bS[SI][2] = *(const bf16x8*)(p_ + 512);                                    \
    bS[SI][3] = *(const bf16x8*)(p_ + 768);                                    \
    bS[SI][4] = *(const bf16x8*)(p_ + 1024);                                   \
    bS[SI][5] = *(const bf16x8*)(p_ + 1280);                                   \
  }

  // A frag for step j (kh=j/5, tl=j%5): local granule 2*tl+h, row prowA+kh
#define LOADA(SL, J)                                                           \
  aR[SL] = *(const bf16x8*)(smem + (((2 * ((J) % 5) + h) * PR) + prowA + (J) / 5) * 16);

#pragma unroll
  for (int p = 0; p < 4; ++p) {
    if (p) __syncthreads();                           // prev phase LDS reads done
    // early B issue (retires with staging barrier)
    LOADB(0, p * 5)
    LOADB(1, p * 5 + 1)
    // stage E phase p: granules p*10..p*10+9 (offset +p*80 elems per slot)
    gload_lds16(smem + tid * 16,            Wb + s0 + p * 80);
    gload_lds16(smem +  4096 + tid * 16,    Wb + s1 + p * 80);
    gload_lds16(smem +  8192 + tid * 16,    Wb + s2 + p * 80);
    gload_lds16(smem + 12288 + tid * 16,    Wb + s3 + p * 80);
    gload_lds16(smem + 16384 + tid * 16,    Wb + s4 + p * 80);
    gload_lds16(smem + 20480 + tid * 16,    Wb + s5 + p * 80);
    gload_lds16(smem + 24576 + tid * 16,    Wb + s6 + p * 80);
    __syncthreads();                                  // drains vmcnt: E + B(0,1) ready
    LOADA(0, 0)
#pragma unroll
    for (int j = 0; j < 15; ++j) {
      if (j + 2 < 15) {
        const int jj = j + 2;
        LOADB(jj % 3, (jj / 5) * 20 + p * 5 + (jj % 5))
      }
      if (j + 1 < 15) { LOADA((j + 1) & 1, j + 1) }
      __builtin_amdgcn_s_setprio(1);
#pragma unroll
      for (int fn = 0; fn < 6; ++fn)
        acc[fn] = __builtin_amdgcn_mfma_f32_32x32x16_bf16(aR[j & 1], bS[j % 3][fn], acc[fn], 0, 0, 0);
      __builtin_amdgcn_s_setprio(0);
    }
  }
#undef LOADA
#undef LOADB

  __syncthreads();                                    // E reads done -> act aliasing safe

  // ---- epilogue: 4 chunks of 32 rows (chunk ch = wave wm==ch, full 192 cols);
  //      bias+relu -> LDS -> per-(row,group) max over 38 channels. Static indices.
#pragma unroll
  for (int ch = 0; ch < 4; ++ch) {
    if (wm == ch) {
#pragma unroll
      for (int fn = 0; fn < 6; ++fn) {
        const int col = fn * 32 + l31;                // < 192 < 210
        const float bias = convb[col];
#pragma unroll
        for (int r = 0; r < 16; ++r) {
          const int row = (r & 3) + 8 * (r >> 2) + 4 * h;   // verified C/D layout (m74/m101)
          act[row * 194 + col] = fmaxf(acc[fn][r] + bias, 0.f);
        }
      }
    }
    __syncthreads();
    if (tid < 160) {                                  // 32 rows x 5 groups
      const int rl = tid / 5, gq = tid - rl * 5;
      const float* ap = act + rl * 194 + gq * KPOOL;
      float mx = 0.f;                                 // relu => values >= 0
#pragma unroll
      for (int i = 0; i < KPOOL; ++i) mx = fmaxf(mx, ap[i]);
      const int m = m0 + ch * 32 + rl;
      const int bb = m / SEQ, ss = m - bb * SEQ;
      maxc[(bb * NBLK + gq) * SEQ + ss] = mx;         // unmasked max; mask applied in k_dense
    }
    __syncthreads();
  }
}

// ---- kernel 4: region-masked dense (120->35) + out (35->35) ----
__global__ __launch_bounds__(256) void k_dense(const float* __restrict__ maxc,
                                               const int* __restrict__ pos,
                                               const float* __restrict__ dw,
                                               const float* __restrict__ db,
                                               const float* __restrict__ ow,
                                               const float* __restrict__ ob,
                                               float* __restrict__ out) {
  __shared__ float dwL[120 * 36];
  __shared__ float owL[35 * 36];
  __shared__ float hL[64 * 36];
  __shared__ float mxL[64 * 40];
  const int tid = threadIdx.x;
  const int r0 = blockIdx.x * 64;                    // 640 blocks x 64 rows
  for (int i = tid; i < 120 * 35; i += 256) { int j = i / 35, d = i - j * 35; dwL[j * 36 + d] = dw[i]; }
  for (int i = tid; i < 35 * 35; i += 256)  { int j = i / 35, d = i - j * 35; owL[j * 36 + d] = ow[i]; }
  for (int i = tid; i < 64 * 40; i += 256)  mxL[i] = maxc[(size_t)r0 * 40 + i];
  __syncthreads();
  for (int t = tid; t < 64 * 35; t += 256) {
    const int row = t / 35, d = t - row * 35;
    const int rg = r0 + row;
    const int b = rg / NBLK;
    const int p0 = pos[b * 2], p1 = pos[b * 2 + 1];
    int e1 = min(p0, p1), e2 = max(p0, p1);
    if (e1 == 0) { e1 = 1; e2 += 1; }
    float a = db[d];
#pragma unroll
    for (int s = 0; s < SEQ; ++s) {
      const int k = (s >= e1) + (s >= e2);           // region of position s
      a += mxL[row * 40 + s] * dwL[(k * SEQ + s) * 36 + d];
    }
    hL[row * 36 + d] = a;
  }
  __syncthreads();
  for (int t = tid; t < 64 * 35; t += 256) {
    const int row = t / 35, c = t - row * 35;
    float a = ob[c];
#pragma unroll
    for (int d = 0; d < DH; ++d) a += hL[row * 36 + d] * owL[d * 36 + c];
    out[(size_t)(r0 + row) * NCLS + c] = a;
  }
}

extern "C" void kernel_launch(void* const* d_in, const int* in_sizes, int n_in,
                              void* d_out, int out_size, void* d_ws, size_t ws_size,
                              hipStream_t stream) {
  const int*   x     = (const int*)d_in[0];
  const int*   pos   = (const int*)d_in[1];
  const float* w2v   = (const float*)d_in[2];
  const float* convw = (const float*)d_in[3];
  const float* convb = (const float*)d_in[4];
  const float* dw    = (const float*)d_in[5];
  const float* db    = (const float*)d_in[6];
  const float* ow    = (const float*)d_in[7];
  const float* ob    = (const float*)d_in[8];
  float* out = (float*)d_out;

  char* ws = (char*)d_ws;
  u16* W    = (u16*)ws;                               // (100001)*320*2 = 64,000,640 B
  u16* Btn  = (u16*)(ws + 64000640);                  // 120*192*8*2   =    368,640 B
  float* maxc = (float*)(ws + 64000640 + 368640);     // 40960*40*4    =  6,553,600 B

  k_prepW<<<15626, 256, 0, stream>>>(w2v, W);         // (100001*40+255)/256
  k_prepB<<<90, 256, 0, stream>>>(convw, Btn);        // 23040/256
  k_conv_gemm<<<2560, 256, 0, stream>>>(W, Btn, x, convb, maxc);  // 327680/128
  k_dense<<<640, 256, 0, stream>>>(maxc, pos, dw, db, ow, ob, out);
}

// Round 14
// 199.373 us; speedup vs baseline: 1.3724x; 1.1591x over previous
//
#include <hip/hip_runtime.h>

typedef short bf16x8 __attribute__((ext_vector_type(8)));
typedef float f32x16 __attribute__((ext_vector_type(16)));
typedef unsigned short u16;
typedef u16 ushort8v __attribute__((ext_vector_type(8)));

// ---- constants ----
#define VOCAB 100000
#define EMB 300
#define SEQ 40
#define BATCH 8192
#define COUT 210
#define NBLK 5
#define KPOOL 38
#define DH 35
#define NCLS 35
#define PCOL 320            // padded w2v row: 300 real + 20 zero (16B-aligned rows)
#define NUSE 192            // only channels 0..189 feed the pool
#define BM 128              // always spans exactly 4 batches
#define PR 172              // padded rows/granule in LDS (168 real + 4; PR%8==4 -> h-halves on disjoint bank sets)
#define NGR 120             // total K granules (3 kh x 40)

__device__ __forceinline__ u16 f2bf(float f) {
  unsigned u = __float_as_uint(f);
  unsigned r = 0x7FFFu + ((u >> 16) & 1u);
  return (u16)((u + r) >> 16);
}

__device__ __forceinline__ void gload_lds16(void* lds, const void* g) {
  __builtin_amdgcn_global_load_lds(
      (const __attribute__((address_space(1))) void*)g,
      (__attribute__((address_space(3))) void*)lds, 16, 0, 0);
}

// ---- kernel 1: w2v f32 [VOCAB][300] -> W bf16 [VOCAB+1][320]; row VOCAB = zeros ----
__global__ __launch_bounds__(256) void k_prepW(const float* __restrict__ w2v,
                                               u16* __restrict__ W) {
  int id = blockIdx.x * 256 + threadIdx.x;          // (VOCAB+1)*40 chunks of 8
  if (id >= (VOCAB + 1) * 40) return;
  int v = id / 40, e8 = id - v * 40;
  int e = e8 * 8;
  float vals[8] = {0.f, 0.f, 0.f, 0.f, 0.f, 0.f, 0.f, 0.f};
  if (v < VOCAB) {
    const float* src = w2v + (size_t)v * EMB + e;
    if (e <= 292) {
      float4 f0 = *(const float4*)src;
      float4 f1 = *(const float4*)(src + 4);
      vals[0] = f0.x; vals[1] = f0.y; vals[2] = f0.z; vals[3] = f0.w;
      vals[4] = f1.x; vals[5] = f1.y; vals[6] = f1.z; vals[7] = f1.w;
    } else if (e == 296) {
      float4 f0 = *(const float4*)src;               // 296..299
      vals[0] = f0.x; vals[1] = f0.y; vals[2] = f0.z; vals[3] = f0.w;
    }
  }
  ushort8v o;
#pragma unroll
  for (int j = 0; j < 8; ++j) o[j] = f2bf(vals[j]);
  *(ushort8v*)(W + (size_t)v * PCOL + e) = o;
}

// ---- kernel 2: conv_w [3][300][210] -> Btn bf16 [120 gran][192 col][8] (zero padded) ----
__global__ __launch_bounds__(256) void k_prepB(const float* __restrict__ convw,
                                               u16* __restrict__ Btn) {
  int id = blockIdx.x * 256 + threadIdx.x;          // 120*192 = 23040
  if (id >= NGR * NUSE) return;
  int gg = id / NUSE, col = id - gg * NUSE;
  ushort8v o;
#pragma unroll
  for (int j = 0; j < 8; ++j) {
    int k = gg * 8 + j;
    int kh = (k >= 640) ? 2 : (k >= 320 ? 1 : 0);
    int e = k - kh * PCOL;
    float v = (e < EMB) ? convw[(kh * EMB + e) * COUT + col] : 0.f;
    o[j] = f2bf(v);
  }
  *(ushort8v*)(Btn + (size_t)id * 8) = o;
}

// ---- kernel 3: fused gather + conv (3 shifted sub-GEMMs) + bias/relu/pool ----
// 32x32x16 MFMA, BM=128 (4 batches), 256 threads = 4 waves as 2M x 2N, wave tile
// 64x96: acc[2][3] f32x16 (96 VGPR). K-sweep = 3 granule-phases (14/14/12 granules):
// per phase, stage [G gran][172 rows]x16B (38,528 B LDS), then 3*G/2 barrier-free
// steps of 2 ds_read_b128 (A) + 3 B-frag loads + 6 MFMA.
// B uses THREE rotating sets: prefetch (j+2)%3, consume j%3 (r13 bug: with 2 sets,
// (j+2)&1 == j&1 -> step j's MFMA consumed step j+2's B tile; r12's 3-set pattern
// is the proven-safe rotation).
__global__ __launch_bounds__(256) void k_conv_gemm(const u16* __restrict__ Wb,
                                                   const u16* __restrict__ Btn,
                                                   const int* __restrict__ x,
                                                   const float* __restrict__ convb,
                                                   float* __restrict__ maxc) {
  __shared__ __align__(16) char smem[14 * PR * 16];   // 38,528 B; epilogue aliases act
  float* act = (float*)smem;                           // [32][194] = 24,832 B

  const int tid = threadIdx.x;
  const int lane = tid & 63;
  const int w = tid >> 6;
  const int wm = w >> 1, wn = w & 1;                  // 2M x 2N wave grid
  const int l31 = lane & 31, h = lane >> 5;
  const int m0 = blockIdx.x * BM;
  const int blo = m0 / SEQ;                           // block spans batches blo..blo+3

  // ---- per-lane A rows (fm=0/1): m = m0 + wm*64 + fm*32 + l31 ----
  int prowA0, prowA1;
  {
    int m = m0 + wm * 64 + l31;
    int bA = m / SEQ, sA = m - bA * SEQ;
    prowA0 = (bA - blo) * 42 + sA;
    m += 32;
    bA = m / SEQ; sA = m - bA * SEQ;
    prowA1 = (bA - blo) * 42 + sA;
  }
  // ---- per-lane B base (elements): k-half h, col = wn*96 + fn*32 + l31 ----
  const int bElem0 = (h * NUSE + wn * 96 + l31) * 8;

  // ---- staging slot offsets: chunk c = ri*256+tid -> (g=c/PR, prow=c%PR) ----
  unsigned sOff[10];
#pragma unroll
  for (int ri = 0; ri < 10; ++ri) {
    const int c = ri * 256 + tid;
    const int g = c / PR, prow = c - g * PR;
    int tok = VOCAB;
    if (prow < 168) {
      const int bb = prow / 42, sp = prow - bb * 42;
      tok = (sp == 0 || sp == 41) ? VOCAB : x[(blo + bb) * SEQ + sp - 1];
    }
    sOff[ri] = (unsigned)tok * PCOL + g * 8;
  }

  f32x16 acc[2][3];
  const f32x16 zero16 = {0.f,0.f,0.f,0.f,0.f,0.f,0.f,0.f,0.f,0.f,0.f,0.f,0.f,0.f,0.f,0.f};
#pragma unroll
  for (int i = 0; i < 2; ++i)
#pragma unroll
    for (int j = 0; j < 3; ++j) acc[i][j] = zero16;

  bf16x8 aR[2][2];                                    // [parity][fm]
  bf16x8 bS[3][3];                                    // [rot3][fn] -- 3 sets, safe rotation

#define LOADA(SL, KH, GP)                                                      \
  aR[SL][0] = *(const bf16x8*)(smem + (((2 * (GP) + h) * PR) + prowA0 + (KH)) * 16); \
  aR[SL][1] = *(const bf16x8*)(smem + (((2 * (GP) + h) * PR) + prowA1 + (KH)) * 16);

#define LOADB(SI, T)                                                           \
  {                                                                            \
    const u16* p_ = Btn + (size_t)(T) * 3072 + bElem0;                         \
    bS[SI][0] = *(const bf16x8*)(p_);                                          \
    bS[SI][1] = *(const bf16x8*)(p_ + 256);                                    \
    bS[SI][2] = *(const bf16x8*)(p_ + 512);                                    \
  }

  // PHASE(GS = start granule, HG = granule pairs, FIRST): stage + 3*HG steps
#define PHASE(GS, HG, FIRST)                                                   \
  {                                                                            \
    if (!(FIRST)) __syncthreads();                    /* prev phase reads done */ \
    LOADB(0, (GS) / 2)                                                         \
    LOADB(1, (GS) / 2 + 1)                                                     \
    _Pragma("unroll")                                                          \
    for (int ri = 0; ri < 10; ++ri) {                                          \
      const int c = ri * 256 + tid;                                            \
      if (c < 2 * (HG) * PR) gload_lds16(smem + c * 16, Wb + sOff[ri] + (GS) * 8); \
    }                                                                          \
    __syncthreads();                                  /* E + B(0,1) resident */ \
    LOADA(0, 0, 0)                                                             \
    _Pragma("unroll")                                                          \
    for (int j = 0; j < 3 * (HG); ++j) {                                       \
      if (j + 1 < 3 * (HG)) {                                                  \
        const int kh1 = (j + 1) / (HG), gp1 = (j + 1) % (HG);                  \
        LOADA((j + 1) & 1, kh1, gp1)                                           \
        if (j + 2 < 3 * (HG)) {                                                \
          const int kh2 = (j + 2) / (HG), gp2 = (j + 2) % (HG);                \
          LOADB((j + 2) % 3, kh2 * 20 + (GS) / 2 + gp2)                        \
        }                                                                      \
      }                                                                        \
      __builtin_amdgcn_s_setprio(1);                                           \
      _Pragma("unroll")                                                        \
      for (int fm = 0; fm < 2; ++fm) {                                         \
        _Pragma("unroll")                                                      \
        for (int fn = 0; fn < 3; ++fn)                                         \
          acc[fm][fn] = __builtin_amdgcn_mfma_f32_32x32x16_bf16(               \
              aR[j & 1][fm], bS[j % 3][fn], acc[fm][fn], 0, 0, 0);             \
      }                                                                        \
      __builtin_amdgcn_s_setprio(0);                                           \
    }                                                                          \
  }

  PHASE(0, 7, 1)                                      // granules  0..13, 21 steps
  PHASE(14, 7, 0)                                     // granules 14..27, 21 steps
  PHASE(28, 6, 0)                                     // granules 28..39, 18 steps

#undef PHASE
#undef LOADA
#undef LOADB

  __syncthreads();                                    // E reads done -> act aliasing safe

  // ---- epilogue: 4 chunks of 32 rows; chunk ch -> wave wm==ch>>1, acc[ch&1];
  //      bias+relu -> LDS -> per-(row,group) max over 38 channels. Static indices.
#pragma unroll
  for (int ch = 0; ch < 4; ++ch) {
    if (wm == (ch >> 1)) {
#pragma unroll
      for (int fn = 0; fn < 3; ++fn) {
        const int col = wn * 96 + fn * 32 + l31;      // < 192 < 210
        const float bias = convb[col];
#pragma unroll
        for (int r = 0; r < 16; ++r) {
          const int row = (r & 3) + 8 * (r >> 2) + 4 * h;   // verified C/D layout (m74/m101)
          act[row * 194 + col] = fmaxf(acc[ch & 1][fn][r] + bias, 0.f);
        }
      }
    }
    __syncthreads();
    if (tid < 160) {                                  // 32 rows x 5 groups
      const int rl = tid / 5, gq = tid - rl * 5;
      const float* ap = act + rl * 194 + gq * KPOOL;
      float mx = 0.f;                                 // relu => values >= 0
#pragma unroll
      for (int i = 0; i < KPOOL; ++i) mx = fmaxf(mx, ap[i]);
      const int m = m0 + ch * 32 + rl;
      const int bb = m / SEQ, ss = m - bb * SEQ;
      maxc[(bb * NBLK + gq) * SEQ + ss] = mx;         // unmasked max; mask applied in k_dense
    }
    __syncthreads();
  }
}

// ---- kernel 4: region-masked dense (120->35) + out (35->35) ----
__global__ __launch_bounds__(256) void k_dense(const float* __restrict__ maxc,
                                               const int* __restrict__ pos,
                                               const float* __restrict__ dw,
                                               const float* __restrict__ db,
                                               const float* __restrict__ ow,
                                               const float* __restrict__ ob,
                                               float* __restrict__ out) {
  __shared__ float dwL[120 * 36];
  __shared__ float owL[35 * 36];
  __shared__ float hL[64 * 36];
  __shared__ float mxL[64 * 40];
  const int tid = threadIdx.x;
  const int r0 = blockIdx.x * 64;                    // 640 blocks x 64 rows
  for (int i = tid; i < 120 * 35; i += 256) { int j = i / 35, d = i - j * 35; dwL[j * 36 + d] = dw[i]; }
  for (int i = tid; i < 35 * 35; i += 256)  { int j = i / 35, d = i - j * 35; owL[j * 36 + d] = ow[i]; }
  for (int i = tid; i < 64 * 40; i += 256)  mxL[i] = maxc[(size_t)r0 * 40 + i];
  __syncthreads();
  for (int t = tid; t < 64 * 35; t += 256) {
    const int row = t / 35, d = t - row * 35;
    const int rg = r0 + row;
    const int b = rg / NBLK;
    const int p0 = pos[b * 2], p1 = pos[b * 2 + 1];
    int e1 = min(p0, p1), e2 = max(p0, p1);
    if (e1 == 0) { e1 = 1; e2 += 1; }
    float a = db[d];
#pragma unroll
    for (int s = 0; s < SEQ; ++s) {
      const int k = (s >= e1) + (s >= e2);           // region of position s
      a += mxL[row * 40 + s] * dwL[(k * SEQ + s) * 36 + d];
    }
    hL[row * 36 + d] = a;
  }
  __syncthreads();
  for (int t = tid; t < 64 * 35; t += 256) {
    const int row = t / 35, c = t - row * 35;
    float a = ob[c];
#pragma unroll
    for (int d = 0; d < DH; ++d) a += hL[row * 36 + d] * owL[d * 36 + c];
    out[(size_t)(r0 + row) * NCLS + c] = a;
  }
}

extern "C" void kernel_launch(void* const* d_in, const int* in_sizes, int n_in,
                              void* d_out, int out_size, void* d_ws, size_t ws_size,
                              hipStream_t stream) {
  const int*   x     = (const int*)d_in[0];
  const int*   pos   = (const int*)d_in[1];
  const float* w2v   = (const float*)d_in[2];
  const float* convw = (const float*)d_in[3];
  const float* convb = (const float*)d_in[4];
  const float* dw    = (const float*)d_in[5];
  const float* db    = (const float*)d_in[6];
  const float* ow    = (const float*)d_in[7];
  const float* ob    = (const float*)d_in[8];
  float* out = (float*)d_out;

  char* ws = (char*)d_ws;
  u16* W    = (u16*)ws;                               // (100001)*320*2 = 64,000,640 B
  u16* Btn  = (u16*)(ws + 64000640);                  // 120*192*8*2   =    368,640 B
  float* maxc = (float*)(ws + 64000640 + 368640);     // 40960*40*4    =  6,553,600 B

  k_prepW<<<15626, 256, 0, stream>>>(w2v, W);         // (100001*40+255)/256
  k_prepB<<<90, 256, 0, stream>>>(convw, Btn);        // 23040/256
  k_conv_gemm<<<2560, 256, 0, stream>>>(W, Btn, x, convb, maxc);  // 327680/128
  k_dense<<<640, 256, 0, stream>>>(maxc, pos, dw, db, ow, ob, out);
}

// Round 15
// 196.365 us; speedup vs baseline: 1.3935x; 1.0153x over previous
//
#include <hip/hip_runtime.h>

typedef short bf16x8 __attribute__((ext_vector_type(8)));
typedef float f32x4 __attribute__((ext_vector_type(4)));
typedef unsigned short u16;
typedef u16 ushort8v __attribute__((ext_vector_type(8)));

// ---- constants ----
#define VOCAB 100000
#define EMB 300
#define SEQ 40
#define BATCH 8192
#define COUT 210
#define NBLK 5
#define KPOOL 38
#define DH 35
#define NCLS 35
#define PCOL 320            // padded w2v row: 300 real + 20 zero (16B-aligned rows)
#define KDIM 960            // 3*320
#define NUSE 192            // only channels 0..189 feed the pool
#define BM 80               // 2 batches per block
#define EROWS 85            // 84 real rows + 1 pad: granule stride (4*85)%32=20 -> l4 groups
                            // hit banks {0,20,8,28}, no cross-group alias (only free 2-way)
#define NGR 120             // KDIM/8 granules

__device__ __forceinline__ u16 f2bf(float f) {
  unsigned u = __float_as_uint(f);
  unsigned r = 0x7FFFu + ((u >> 16) & 1u);
  return (u16)((u + r) >> 16);
}

__device__ __forceinline__ void gload_lds16(void* lds, const void* g) {
  __builtin_amdgcn_global_load_lds(
      (const __attribute__((address_space(1))) void*)g,
      (__attribute__((address_space(3))) void*)lds, 16, 0, 0);
}

// ---- kernel 1: w2v f32 [VOCAB][300] -> W bf16 [VOCAB+1][320]; row VOCAB = zeros ----
__global__ __launch_bounds__(256) void k_prepW(const float* __restrict__ w2v,
                                               u16* __restrict__ W) {
  int id = blockIdx.x * 256 + threadIdx.x;          // (VOCAB+1)*40 chunks of 8
  if (id >= (VOCAB + 1) * 40) return;
  int v = id / 40, e8 = id - v * 40;
  int e = e8 * 8;
  float vals[8] = {0.f, 0.f, 0.f, 0.f, 0.f, 0.f, 0.f, 0.f};
  if (v < VOCAB) {
    const float* src = w2v + (size_t)v * EMB + e;
    if (e <= 292) {
      float4 f0 = *(const float4*)src;
      float4 f1 = *(const float4*)(src + 4);
      vals[0] = f0.x; vals[1] = f0.y; vals[2] = f0.z; vals[3] = f0.w;
      vals[4] = f1.x; vals[5] = f1.y; vals[6] = f1.z; vals[7] = f1.w;
    } else if (e == 296) {
      float4 f0 = *(const float4*)src;               // 296..299
      vals[0] = f0.x; vals[1] = f0.y; vals[2] = f0.z; vals[3] = f0.w;
    }
  }
  ushort8v o;
#pragma unroll
  for (int j = 0; j < 8; ++j) o[j] = f2bf(vals[j]);
  *(ushort8v*)(W + (size_t)v * PCOL + e) = o;
}

// ---- kernel 2: conv_w [3][300][210] -> Btn bf16 [120 gran][192 col][8] (zero padded) ----
__global__ __launch_bounds__(256) void k_prepB(const float* __restrict__ convw,
                                               u16* __restrict__ Btn) {
  int id = blockIdx.x * 256 + threadIdx.x;          // 120*192 = 23040
  if (id >= NGR * NUSE) return;
  int gg = id / NUSE, col = id - gg * NUSE;
  ushort8v o;
#pragma unroll
  for (int j = 0; j < 8; ++j) {
    int k = gg * 8 + j;
    int kh = (k >= 640) ? 2 : (k >= 320 ? 1 : 0);
    int e = k - kh * PCOL;
    float v = (e < EMB) ? convw[(kh * EMB + e) * COUT + col] : 0.f;
    o[j] = f2bf(v);
  }
  *(ushort8v*)(Btn + (size_t)id * 8) = o;
}

// ---- kernel 3: fused gather + conv (3 shifted K=320 sub-GEMMs) + bias/relu/pool ----
// r7 structure (proven best: stage E-tile ONCE, then 30 barrier-free steps) plus:
// (a) A-frag ping-pong prefetch aR[2][5] - step t+1's 5 ds_read_b128 issue during
//     step t's 15 MFMAs (parity-disjoint; B keeps proven 3-set (t+2)%3 rotation);
// (b) EROWS 84->85 kills the (4*84)%32=16 granule-stride bank alias (was 4-way).
// 4 waves (1M x 4N), wave tile 80x48: acc[5][3]; B direct global->VGPR from L2.
__global__ __launch_bounds__(256) void k_conv_gemm(const u16* __restrict__ Wb,
                                                   const u16* __restrict__ Btn,
                                                   const int* __restrict__ x,
                                                   const float* __restrict__ convb,
                                                   float* __restrict__ maxc) {
  __shared__ __align__(16) char smem[40 * EROWS * 16];   // 54,400 B; epilogue aliases act
  float* act = (float*)smem;                             // [16][194] per chunk

  const int tid = threadIdx.x;
  const int lane = tid & 63;
  const int wc = tid >> 6;                          // wave = N-slot 0..3
  const int l15 = lane & 15, l4 = lane >> 4;
  const int b0 = blockIdx.x * 2;

  // ---- prologue: gather E-tile, dest-linear chunks d=(g*85+prow), 3400 total ----
  // prow 0..41 = batch b0 (sp 0/41 pads), 42..83 = batch b0+1, 84 = pad row.
#pragma unroll
  for (int ri = 0; ri < 13; ++ri) {
    const int d = ri * 256 + tid;                   // 0..3327
    const int g = d / EROWS, prow = d - g * EROWS;
    int tok = VOCAB;
    if (prow < 84) {
      const int bb = prow / 42, sp = prow - bb * 42;
      tok = (sp == 0 || sp == 41) ? VOCAB : x[(b0 + bb) * SEQ + sp - 1];
    }
    gload_lds16(smem + d * 16, Wb + (size_t)tok * PCOL + g * 8);
  }
  if (tid < 72) {                                   // 3328..3399
    const int d = 3328 + tid;
    const int g = d / EROWS, prow = d - g * EROWS;
    int tok = VOCAB;
    if (prow < 84) {
      const int bb = prow / 42, sp = prow - bb * 42;
      tok = (sp == 0 || sp == 41) ? VOCAB : x[(b0 + bb) * SEQ + sp - 1];
    }
    gload_lds16(smem + d * 16, Wb + (size_t)tok * PCOL + g * 8);
  }

  // ---- per-lane A row indices (fold batch-boundary pad jump) ----
  const int rA0 = l15;                              // fm=0: batch0 s=l15
  const int rA1 = 16 + l15;                         // fm=1
  const int rA2 = 32 + l15 + ((l15 >= 8) ? 2 : 0);  // fm=2 straddles batch boundary
  const int rA3 = 50 + l15;                         // fm=3
  const int rA4 = 66 + l15;                         // fm=4

  // ---- B setup: frag (granule 4T+l4, col wc*48+fn*16+l15); tile T at +T*6144 ----
  const u16* pbB = Btn + (size_t)((l4 * NUSE) + wc * 48 + l15) * 8;

  f32x4 acc[5][3];
  const f32x4 zero = {0.f, 0.f, 0.f, 0.f};
#pragma unroll
  for (int i = 0; i < 5; ++i)
#pragma unroll
    for (int j = 0; j < 3; ++j) acc[i][j] = zero;

  bf16x8 aR[2][5];                                  // ping-pong A sets (80 VGPR)
  bf16x8 bs[3][3];                                  // 3 rotating B sets

#define LOADB(SI, T)                                                           \
  {                                                                            \
    const u16* p_ = pbB + (size_t)(T) * 6144;                                  \
    bs[SI][0] = *(const bf16x8*)(p_);                                          \
    bs[SI][1] = *(const bf16x8*)(p_ + 128);                                    \
    bs[SI][2] = *(const bf16x8*)(p_ + 256);                                    \
  }

  // A frags for step T (kh=T/10, kq=T%10): granule kq*4+l4, rows rA_i + kh
#define LOADA(SL, T)                                                           \
  {                                                                            \
    const char* kb_ = smem + ((((T) % 10) * 4 + l4) * EROWS + (T) / 10) * 16;  \
    aR[SL][0] = *(const bf16x8*)(kb_ + rA0 * 16);                              \
    aR[SL][1] = *(const bf16x8*)(kb_ + rA1 * 16);                              \
    aR[SL][2] = *(const bf16x8*)(kb_ + rA2 * 16);                              \
    aR[SL][3] = *(const bf16x8*)(kb_ + rA3 * 16);                              \
    aR[SL][4] = *(const bf16x8*)(kb_ + rA4 * 16);                              \
  }

  LOADB(0, 0)
  LOADB(1, 1)
  __syncthreads();                                  // E-tile resident (drains vmcnt)
  LOADA(0, 0)

#pragma unroll
  for (int t = 0; t < 30; ++t) {
    if (t + 1 < 30) { LOADA((t + 1) & 1, t + 1) }   // prefetch next A during MFMAs
    if (t + 2 < 30) { LOADB((t + 2) % 3, t + 2) }
    __builtin_amdgcn_s_setprio(1);
#pragma unroll
    for (int fn = 0; fn < 3; ++fn) {
      acc[0][fn] = __builtin_amdgcn_mfma_f32_16x16x32_bf16(aR[t & 1][0], bs[t % 3][fn], acc[0][fn], 0, 0, 0);
      acc[1][fn] = __builtin_amdgcn_mfma_f32_16x16x32_bf16(aR[t & 1][1], bs[t % 3][fn], acc[1][fn], 0, 0, 0);
      acc[2][fn] = __builtin_amdgcn_mfma_f32_16x16x32_bf16(aR[t & 1][2], bs[t % 3][fn], acc[2][fn], 0, 0, 0);
      acc[3][fn] = __builtin_amdgcn_mfma_f32_16x16x32_bf16(aR[t & 1][3], bs[t % 3][fn], acc[3][fn], 0, 0, 0);
      acc[4][fn] = __builtin_amdgcn_mfma_f32_16x16x32_bf16(aR[t & 1][4], bs[t % 3][fn], acc[4][fn], 0, 0, 0);
    }
    __builtin_amdgcn_s_setprio(0);
  }
#undef LOADA
#undef LOADB

  __syncthreads();                                  // all E reads done -> act aliasing safe

  // ---- epilogue: 5 chunks of 16 rows (one per fm); bias+relu -> LDS -> channel-group max ----
#pragma unroll
  for (int fm = 0; fm < 5; ++fm) {
#pragma unroll
    for (int fn = 0; fn < 3; ++fn) {
      const int col = wc * 48 + fn * 16 + l15;      // < 192 < 210
      const float bias = convb[col];
#pragma unroll
      for (int rg = 0; rg < 4; ++rg) {
        const int rloc = l4 * 4 + rg;               // 0..15 within chunk
        float vv = acc[fm][fn][rg] + bias;
        act[rloc * 194 + col] = fmaxf(vv, 0.f);
      }
    }
    __syncthreads();
    if (tid < 80) {                                 // 16 rows x 5 groups
      const int rl = tid / 5, gq = tid - rl * 5;
      const float* ap = act + rl * 194 + gq * KPOOL;
      float mx = 0.f;                               // relu => values >= 0
#pragma unroll
      for (int i = 0; i < KPOOL; ++i) mx = fmaxf(mx, ap[i]);
      const int mloc = fm * 16 + rl;
      const int bb = (mloc >= 40) ? 1 : 0;
      const int ss = mloc - 40 * bb;
      maxc[((b0 + bb) * NBLK + gq) * SEQ + ss] = mx; // unmasked max; mask applied in k_dense
    }
    __syncthreads();
  }
}

// ---- kernel 4: region-masked dense (120->35) + out (35->35) ----
__global__ __launch_bounds__(256) void k_dense(const float* __restrict__ maxc,
                                               const int* __restrict__ pos,
                                               const float* __restrict__ dw,
                                               const float* __restrict__ db,
                                               const float* __restrict__ ow,
                                               const float* __restrict__ ob,
                                               float* __restrict__ out) {
  __shared__ float dwL[120 * 36];
  __shared__ float owL[35 * 36];
  __shared__ float hL[64 * 36];
  __shared__ float mxL[64 * 40];
  const int tid = threadIdx.x;
  const int r0 = blockIdx.x * 64;                    // 640 blocks x 64 rows
  for (int i = tid; i < 120 * 35; i += 256) { int j = i / 35, d = i - j * 35; dwL[j * 36 + d] = dw[i]; }
  for (int i = tid; i < 35 * 35; i += 256)  { int j = i / 35, d = i - j * 35; owL[j * 36 + d] = ow[i]; }
  for (int i = tid; i < 64 * 40; i += 256)  mxL[i] = maxc[(size_t)r0 * 40 + i];
  __syncthreads();
  for (int t = tid; t < 64 * 35; t += 256) {
    const int row = t / 35, d = t - row * 35;
    const int rg = r0 + row;
    const int b = rg / NBLK;
    const int p0 = pos[b * 2], p1 = pos[b * 2 + 1];
    int e1 = min(p0, p1), e2 = max(p0, p1);
    if (e1 == 0) { e1 = 1; e2 += 1; }
    float a = db[d];
#pragma unroll
    for (int s = 0; s < SEQ; ++s) {
      const int k = (s >= e1) + (s >= e2);           // region of position s
      a += mxL[row * 40 + s] * dwL[(k * SEQ + s) * 36 + d];
    }
    hL[row * 36 + d] = a;
  }
  __syncthreads();
  for (int t = tid; t < 64 * 35; t += 256) {
    const int row = t / 35, c = t - row * 35;
    float a = ob[c];
#pragma unroll
    for (int d = 0; d < DH; ++d) a += hL[row * 36 + d] * owL[d * 36 + c];
    out[(size_t)(r0 + row) * NCLS + c] = a;
  }
}

extern "C" void kernel_launch(void* const* d_in, const int* in_sizes, int n_in,
                              void* d_out, int out_size, void* d_ws, size_t ws_size,
                              hipStream_t stream) {
  const int*   x     = (const int*)d_in[0];
  const int*   pos   = (const int*)d_in[1];
  const float* w2v   = (const float*)d_in[2];
  const float* convw = (const float*)d_in[3];
  const float* convb = (const float*)d_in[4];
  const float* dw    = (const float*)d_in[5];
  const float* db    = (const float*)d_in[6];
  const float* ow    = (const float*)d_in[7];
  const float* ob    = (const float*)d_in[8];
  float* out = (float*)d_out;

  char* ws = (char*)d_ws;
  u16* W    = (u16*)ws;                               // (100001)*320*2 = 64,000,640 B
  u16* Btn  = (u16*)(ws + 64000640);                  // 120*192*8*2   =    368,640 B
  float* maxc = (float*)(ws + 64000640 + 368640);     // 40960*40*4    =  6,553,600 B

  k_prepW<<<15626, 256, 0, stream>>>(w2v, W);         // (100001*40+255)/256
  k_prepB<<<90, 256, 0, stream>>>(convw, Btn);        // 23040/256
  k_conv_gemm<<<4096, 256, 0, stream>>>(W, Btn, x, convb, maxc);  // 327680/80
  k_dense<<<640, 256, 0, stream>>>(maxc, pos, dw, db, ow, ob, out);
}

// Round 16
// 182.709 us; speedup vs baseline: 1.4976x; 1.0747x over previous
//
#include <hip/hip_runtime.h>

typedef short bf16x8 __attribute__((ext_vector_type(8)));
typedef float f32x4 __attribute__((ext_vector_type(4)));
typedef unsigned short u16;
typedef u16 ushort8v __attribute__((ext_vector_type(8)));

// ---- constants ----
#define VOCAB 100000
#define EMB 300
#define SEQ 40
#define BATCH 8192
#define COUT 210
#define NBLK 5
#define KPOOL 38
#define DH 35
#define NCLS 35
#define PCOL 320            // padded w2v row: 300 real + 20 zero (16B-aligned rows)
#define KDIM 960            // 3*320
#define NUSE 192            // only channels 0..189 feed the pool
#define BM 80               // 2 batches per block
#define EROWS 84            // 2 x 42 padded rows; LDS 53,760 B -> 3 blocks/CU (r15 lesson:
                            // 85 rows = 54,784 B crosses the 3-block boundary, -9 occ pts)
#define ASTR 197            // act row stride (odd -> pool reads spread all 32 banks;
                            // 194 gave bank=(2rl+6gq+i)%32: even-only, 4-6-way conflicts)
#define NGR 120             // KDIM/8 granules

__device__ __forceinline__ u16 f2bf(float f) {
  unsigned u = __float_as_uint(f);
  unsigned r = 0x7FFFu + ((u >> 16) & 1u);
  return (u16)((u + r) >> 16);
}

__device__ __forceinline__ void gload_lds16(void* lds, const void* g) {
  __builtin_amdgcn_global_load_lds(
      (const __attribute__((address_space(1))) void*)g,
      (__attribute__((address_space(3))) void*)lds, 16, 0, 0);
}

// ---- kernel 1: w2v f32 [VOCAB][300] -> W bf16 [VOCAB+1][320]; row VOCAB = zeros ----
__global__ __launch_bounds__(256) void k_prepW(const float* __restrict__ w2v,
                                               u16* __restrict__ W) {
  int id = blockIdx.x * 256 + threadIdx.x;          // (VOCAB+1)*40 chunks of 8
  if (id >= (VOCAB + 1) * 40) return;
  int v = id / 40, e8 = id - v * 40;
  int e = e8 * 8;
  float vals[8] = {0.f, 0.f, 0.f, 0.f, 0.f, 0.f, 0.f, 0.f};
  if (v < VOCAB) {
    const float* src = w2v + (size_t)v * EMB + e;
    if (e <= 292) {
      float4 f0 = *(const float4*)src;
      float4 f1 = *(const float4*)(src + 4);
      vals[0] = f0.x; vals[1] = f0.y; vals[2] = f0.z; vals[3] = f0.w;
      vals[4] = f1.x; vals[5] = f1.y; vals[6] = f1.z; vals[7] = f1.w;
    } else if (e == 296) {
      float4 f0 = *(const float4*)src;               // 296..299
      vals[0] = f0.x; vals[1] = f0.y; vals[2] = f0.z; vals[3] = f0.w;
    }
  }
  ushort8v o;
#pragma unroll
  for (int j = 0; j < 8; ++j) o[j] = f2bf(vals[j]);
  *(ushort8v*)(W + (size_t)v * PCOL + e) = o;
}

// ---- kernel 2: conv_w [3][300][210] -> Btn bf16 [120 gran][192 col][8] (zero padded) ----
__global__ __launch_bounds__(256) void k_prepB(const float* __restrict__ convw,
                                               u16* __restrict__ Btn) {
  int id = blockIdx.x * 256 + threadIdx.x;          // 120*192 = 23040
  if (id >= NGR * NUSE) return;
  int gg = id / NUSE, col = id - gg * NUSE;
  ushort8v o;
#pragma unroll
  for (int j = 0; j < 8; ++j) {
    int k = gg * 8 + j;
    int kh = (k >= 640) ? 2 : (k >= 320 ? 1 : 0);
    int e = k - kh * PCOL;
    float v = (e < EMB) ? convw[(kh * EMB + e) * COUT + col] : 0.f;
    o[j] = f2bf(v);
  }
  *(ushort8v*)(Btn + (size_t)id * 8) = o;
}

// ---- kernel 3: fused gather + conv (3 shifted K=320 sub-GEMMs) + bias/relu/pool ----
// r7 geometry (EROWS=84, 53,760 B LDS, 3 blocks/CU) + r15's A ping-pong prefetch
// (step t+1's 5 ds_read_b128 issue under step t's 15 MFMAs) + odd act stride (197).
// 4 waves (1M x 4N), wave tile 80x48: acc[5][3]; B direct global->VGPR, 3-set rotation.
__global__ __launch_bounds__(256) void k_conv_gemm(const u16* __restrict__ Wb,
                                                   const u16* __restrict__ Btn,
                                                   const int* __restrict__ x,
                                                   const float* __restrict__ convb,
                                                   float* __restrict__ maxc) {
  __shared__ __align__(16) char smem[40 * EROWS * 16];   // 53,760 B; epilogue aliases act
  float* act = (float*)smem;                             // [16][197] per chunk

  const int tid = threadIdx.x;
  const int lane = tid & 63;
  const int wc = tid >> 6;                          // wave = N-slot 0..3
  const int l15 = lane & 15, l4 = lane >> 4;
  const int b0 = blockIdx.x * 2;

  // ---- prologue: gather E-tile, chunk d=(g*84+prow), 3360 total ----
  // prow 0..41 = batch b0 (sp 0/41 pads), 42..83 = batch b0+1.
#pragma unroll
  for (int ri = 0; ri < 13; ++ri) {
    const int d = ri * 256 + tid;                   // 0..3327
    const int g = d / EROWS, prow = d - g * EROWS;
    const int bb = prow / 42, sp = prow - bb * 42;
    const int tok = (sp == 0 || sp == 41) ? VOCAB : x[(b0 + bb) * SEQ + sp - 1];
    gload_lds16(smem + d * 16, Wb + (size_t)tok * PCOL + g * 8);
  }
  if (tid < 32) {                                   // 3328..3359
    const int d = 3328 + tid;
    const int g = d / EROWS, prow = d - g * EROWS;
    const int bb = prow / 42, sp = prow - bb * 42;
    const int tok = (sp == 0 || sp == 41) ? VOCAB : x[(b0 + bb) * SEQ + sp - 1];
    gload_lds16(smem + d * 16, Wb + (size_t)tok * PCOL + g * 8);
  }

  // ---- per-lane A row indices (fold batch-boundary pad jump) ----
  const int rA0 = l15;                              // fm=0
  const int rA1 = 16 + l15;                         // fm=1
  const int rA2 = 32 + l15 + ((l15 >= 8) ? 2 : 0);  // fm=2 straddles batch boundary
  const int rA3 = 50 + l15;                         // fm=3
  const int rA4 = 66 + l15;                         // fm=4

  // ---- B setup: frag (granule 4T+l4, col wc*48+fn*16+l15); tile T at +T*6144 ----
  const u16* pbB = Btn + (size_t)((l4 * NUSE) + wc * 48 + l15) * 8;

  f32x4 acc[5][3];
  const f32x4 zero = {0.f, 0.f, 0.f, 0.f};
#pragma unroll
  for (int i = 0; i < 5; ++i)
#pragma unroll
    for (int j = 0; j < 3; ++j) acc[i][j] = zero;

  bf16x8 aR[2][5];                                  // ping-pong A sets (80 VGPR)
  bf16x8 bs[3][3];                                  // 3 rotating B sets

#define LOADB(SI, T)                                                           \
  {                                                                            \
    const u16* p_ = pbB + (size_t)(T) * 6144;                                  \
    bs[SI][0] = *(const bf16x8*)(p_);                                          \
    bs[SI][1] = *(const bf16x8*)(p_ + 128);                                    \
    bs[SI][2] = *(const bf16x8*)(p_ + 256);                                    \
  }

  // A frags for step T (kh=T/10, kq=T%10): granule kq*4+l4, rows rA_i + kh
#define LOADA(SL, T)                                                           \
  {                                                                            \
    const char* kb_ = smem + ((((T) % 10) * 4 + l4) * EROWS + (T) / 10) * 16;  \
    aR[SL][0] = *(const bf16x8*)(kb_ + rA0 * 16);                              \
    aR[SL][1] = *(const bf16x8*)(kb_ + rA1 * 16);                              \
    aR[SL][2] = *(const bf16x8*)(kb_ + rA2 * 16);                              \
    aR[SL][3] = *(const bf16x8*)(kb_ + rA3 * 16);                              \
    aR[SL][4] = *(const bf16x8*)(kb_ + rA4 * 16);                              \
  }

  LOADB(0, 0)
  LOADB(1, 1)
  __syncthreads();                                  // E-tile resident (drains vmcnt)
  LOADA(0, 0)

#pragma unroll
  for (int t = 0; t < 30; ++t) {
    if (t + 1 < 30) { LOADA((t + 1) & 1, t + 1) }   // prefetch next A during MFMAs
    if (t + 2 < 30) { LOADB((t + 2) % 3, t + 2) }
    __builtin_amdgcn_s_setprio(1);
#pragma unroll
    for (int fn = 0; fn < 3; ++fn) {
      acc[0][fn] = __builtin_amdgcn_mfma_f32_16x16x32_bf16(aR[t & 1][0], bs[t % 3][fn], acc[0][fn], 0, 0, 0);
      acc[1][fn] = __builtin_amdgcn_mfma_f32_16x16x32_bf16(aR[t & 1][1], bs[t % 3][fn], acc[1][fn], 0, 0, 0);
      acc[2][fn] = __builtin_amdgcn_mfma_f32_16x16x32_bf16(aR[t & 1][2], bs[t % 3][fn], acc[2][fn], 0, 0, 0);
      acc[3][fn] = __builtin_amdgcn_mfma_f32_16x16x32_bf16(aR[t & 1][3], bs[t % 3][fn], acc[3][fn], 0, 0, 0);
      acc[4][fn] = __builtin_amdgcn_mfma_f32_16x16x32_bf16(aR[t & 1][4], bs[t % 3][fn], acc[4][fn], 0, 0, 0);
    }
    __builtin_amdgcn_s_setprio(0);
  }
#undef LOADA
#undef LOADB

  __syncthreads();                                  // all E reads done -> act aliasing safe

  // ---- epilogue: 5 chunks of 16 rows (one per fm); bias+relu -> LDS -> channel-group max ----
#pragma unroll
  for (int fm = 0; fm < 5; ++fm) {
#pragma unroll
    for (int fn = 0; fn < 3; ++fn) {
      const int col = wc * 48 + fn * 16 + l15;      // < 192 < 210
      const float bias = convb[col];
#pragma unroll
      for (int rg = 0; rg < 4; ++rg) {
        const int rloc = l4 * 4 + rg;               // 0..15 within chunk
        float vv = acc[fm][fn][rg] + bias;
        act[rloc * ASTR + col] = fmaxf(vv, 0.f);
      }
    }
    __syncthreads();
    if (tid < 80) {                                 // 16 rows x 5 groups
      const int rl = tid / 5, gq = tid - rl * 5;
      const float* ap = act + rl * ASTR + gq * KPOOL;
      float mx = 0.f;                               // relu => values >= 0
#pragma unroll
      for (int i = 0; i < KPOOL; ++i) mx = fmaxf(mx, ap[i]);
      const int mloc = fm * 16 + rl;
      const int bb = (mloc >= 40) ? 1 : 0;
      const int ss = mloc - 40 * bb;
      maxc[((b0 + bb) * NBLK + gq) * SEQ + ss] = mx; // unmasked max; mask applied in k_dense
    }
    __syncthreads();
  }
}

// ---- kernel 4: region-masked dense (120->35) + out (35->35) ----
__global__ __launch_bounds__(256) void k_dense(const float* __restrict__ maxc,
                                               const int* __restrict__ pos,
                                               const float* __restrict__ dw,
                                               const float* __restrict__ db,
                                               const float* __restrict__ ow,
                                               const float* __restrict__ ob,
                                               float* __restrict__ out) {
  __shared__ float dwL[120 * 36];
  __shared__ float owL[35 * 36];
  __shared__ float hL[64 * 36];
  __shared__ float mxL[64 * 40];
  const int tid = threadIdx.x;
  const int r0 = blockIdx.x * 64;                    // 640 blocks x 64 rows
  for (int i = tid; i < 120 * 35; i += 256) { int j = i / 35, d = i - j * 35; dwL[j * 36 + d] = dw[i]; }
  for (int i = tid; i < 35 * 35; i += 256)  { int j = i / 35, d = i - j * 35; owL[j * 36 + d] = ow[i]; }
  for (int i = tid; i < 64 * 40; i += 256)  mxL[i] = maxc[(size_t)r0 * 40 + i];
  __syncthreads();
  for (int t = tid; t < 64 * 35; t += 256) {
    const int row = t / 35, d = t - row * 35;
    const int rg = r0 + row;
    const int b = rg / NBLK;
    const int p0 = pos[b * 2], p1 = pos[b * 2 + 1];
    int e1 = min(p0, p1), e2 = max(p0, p1);
    if (e1 == 0) { e1 = 1; e2 += 1; }
    float a = db[d];
#pragma unroll
    for (int s = 0; s < SEQ; ++s) {
      const int k = (s >= e1) + (s >= e2);           // region of position s
      a += mxL[row * 40 + s] * dwL[(k * SEQ + s) * 36 + d];
    }
    hL[row * 36 + d] = a;
  }
  __syncthreads();
  for (int t = tid; t < 64 * 35; t += 256) {
    const int row = t / 35, c = t - row * 35;
    float a = ob[c];
#pragma unroll
    for (int d = 0; d < DH; ++d) a += hL[row * 36 + d] * owL[d * 36 + c];
    out[(size_t)(r0 + row) * NCLS + c] = a;
  }
}

extern "C" void kernel_launch(void* const* d_in, const int* in_sizes, int n_in,
                              void* d_out, int out_size, void* d_ws, size_t ws_size,
                              hipStream_t stream) {
  const int*   x     = (const int*)d_in[0];
  const int*   pos   = (const int*)d_in[1];
  const float* w2v   = (const float*)d_in[2];
  const float* convw = (const float*)d_in[3];
  const float* convb = (const float*)d_in[4];
  const float* dw    = (const float*)d_in[5];
  const float* db    = (const float*)d_in[6];
  const float* ow    = (const float*)d_in[7];
  const float* ob    = (const float*)d_in[8];
  float* out = (float*)d_out;

  char* ws = (char*)d_ws;
  u16* W    = (u16*)ws;                               // (100001)*320*2 = 64,000,640 B
  u16* Btn  = (u16*)(ws + 64000640);                  // 120*192*8*2   =    368,640 B
  float* maxc = (float*)(ws + 64000640 + 368640);     // 40960*40*4    =  6,553,600 B

  k_prepW<<<15626, 256, 0, stream>>>(w2v, W);         // (100001*40+255)/256
  k_prepB<<<90, 256, 0, stream>>>(convw, Btn);        // 23040/256
  k_conv_gemm<<<4096, 256, 0, stream>>>(W, Btn, x, convb, maxc);  // 327680/80
  k_dense<<<640, 256, 0, stream>>>(maxc, pos, dw, db, ow, ob, out);
}